// Round 4
// baseline (2499.956 us; speedup 1.0000x reference)
//
#include <hip/hip_runtime.h>
#include <math.h>

typedef unsigned short u16;
typedef unsigned int u32;
typedef __bf16 bf16x8 __attribute__((ext_vector_type(8)));
typedef float f32x4 __attribute__((ext_vector_type(4)));

#define DIM 512
#define D_IN 4096
#define N_OBJS 2048
#define N_RELS 32768
#define N_OBJ_CLS 151
#define N_REL_CLS 51
#define EPSV 1e-5f

// d_out layout (floats)
#define OFF_HOBJ  0
#define OFF_HEDGE (N_OBJS*DIM)
#define OFF_OLOG  (OFF_HEDGE + N_RELS*DIM)
#define OFF_PLOG  (OFF_OLOG + N_OBJS*N_OBJ_CLS)
#define OFF_LBL   (OFF_PLOG + N_RELS*N_REL_CLS)
#define OFF_RI    (OFF_LBL + N_OBJS)

__device__ __forceinline__ float sigmoidf_(float x) { return 1.0f / (1.0f + expf(-x)); }
__device__ __forceinline__ u16 f2bf(float f) {          // fp32 -> bf16 RNE
    u32 u = __float_as_uint(f);
    return (u16)((u + 0x7FFFu + ((u >> 16) & 1u)) >> 16);
}
__device__ __forceinline__ float bf2f(u16 h) { return __uint_as_float(((u32)h) << 16); }

// convert 8 fp32 -> packed hi/lo bf16 (uint4 each)
__device__ __forceinline__ void cvt8(const float* f, uint4& h, uint4& l) {
    u32 hh[8], ll[8];
#pragma unroll
    for (int i = 0; i < 8; i++) {
        u16 x = f2bf(f[i]);
        hh[i] = x;
        ll[i] = f2bf(f[i] - bf2f(x));
    }
    h.x = hh[0] | (hh[1] << 16); h.y = hh[2] | (hh[3] << 16);
    h.z = hh[4] | (hh[5] << 16); h.w = hh[6] | (hh[7] << 16);
    l.x = ll[0] | (ll[1] << 16); l.y = ll[2] | (ll[3] << 16);
    l.z = ll[4] | (ll[5] << 16); l.w = ll[6] | (ll[7] << 16);
}

// LDS offset (u16 units) for (row, chunk8) in a [rows][32]-bf16 tile,
// XOR-swizzled: chunk' = chunk ^ ((row>>1)&3)  -> 2-way conflicts max (free)
__device__ __forceinline__ int swzo(int row, int c) {
    return row * 32 + ((c ^ ((row >> 1) & 3)) << 3);
}

// ---------------------------------------------------------------------------
// fp32 -> (hi,lo) bf16 split, flat array (n4 = n/4 float4 elements)
// ---------------------------------------------------------------------------
__global__ __launch_bounds__(256) void convert_split(const float* __restrict__ src,
    u16* __restrict__ hi, u16* __restrict__ lo, int n4)
{
    const int i = blockIdx.x * 256 + threadIdx.x;
    if (i >= n4) return;
    const float4 v = ((const float4*)src)[i];
    u16 h0 = f2bf(v.x), h1 = f2bf(v.y), h2 = f2bf(v.z), h3 = f2bf(v.w);
    u16 l0 = f2bf(v.x - bf2f(h0)), l1 = f2bf(v.y - bf2f(h1));
    u16 l2 = f2bf(v.z - bf2f(h2)), l3 = f2bf(v.w - bf2f(h3));
    ((ushort4*)hi)[i] = make_ushort4(h0, h1, h2, h3);
    ((ushort4*)lo)[i] = make_ushort4(l0, l1, l2, l3);
}

// ---------------------------------------------------------------------------
// Split-bf16 MFMA GEMM (fp32 A, on-the-fly split): C = act(A @ Bsplit^T + bias)
// 128x128 tile, 4 waves (wave tile 64x64), BK=32, 16x16x32 bf16 MFMA.
// ---------------------------------------------------------------------------
template<bool RELU>
__global__ __launch_bounds__(256, 2) void gemm_split(
    const float* __restrict__ A, const u16* __restrict__ Bhi, const u16* __restrict__ Blo,
    const float* __restrict__ bias, float* __restrict__ C, int M, int N, int K)
{
    __shared__ u16 sAh[128 * 32], sAl[128 * 32], sBh[128 * 32], sBl[128 * 32];
    const int t = threadIdx.x;
    const int m0 = blockIdx.y * 128, n0 = blockIdx.x * 128;
    const int wid = t >> 6, lane = t & 63;
    const int wm = (wid >> 1) * 64, wn = (wid & 1) * 64;
    const int lr = lane & 15, lk = lane >> 4;

    f32x4 acc[4][4] = {};

    const int sr = t >> 1;
    const int sc = (t & 1) * 2;
    const float* Ap = A + (size_t)(m0 + sr) * K + (t & 1) * 16;
    const bool bvalid = (n0 + sr) < N;
    const u16* Bhp = Bhi + (size_t)(bvalid ? (n0 + sr) : 0) * K + (t & 1) * 16;
    const u16* Blp = Blo + (size_t)(bvalid ? (n0 + sr) : 0) * K + (t & 1) * 16;

    for (int k0 = 0; k0 < K; k0 += 32) {
        float fv[16];
        *(float4*)&fv[0]  = *(const float4*)(Ap + k0);
        *(float4*)&fv[4]  = *(const float4*)(Ap + k0 + 4);
        *(float4*)&fv[8]  = *(const float4*)(Ap + k0 + 8);
        *(float4*)&fv[12] = *(const float4*)(Ap + k0 + 12);
        uint4 bh0 = {0,0,0,0}, bh1 = {0,0,0,0}, bl0 = {0,0,0,0}, bl1 = {0,0,0,0};
        if (bvalid) {
            bh0 = *(const uint4*)(Bhp + k0); bh1 = *(const uint4*)(Bhp + k0 + 8);
            bl0 = *(const uint4*)(Blp + k0); bl1 = *(const uint4*)(Blp + k0 + 8);
        }
        uint4 ah0, ah1, al0, al1;
        cvt8(fv, ah0, al0); cvt8(fv + 8, ah1, al1);

        __syncthreads();
        *(uint4*)&sAh[swzo(sr, sc)]     = ah0;
        *(uint4*)&sAh[swzo(sr, sc + 1)] = ah1;
        *(uint4*)&sAl[swzo(sr, sc)]     = al0;
        *(uint4*)&sAl[swzo(sr, sc + 1)] = al1;
        *(uint4*)&sBh[swzo(sr, sc)]     = bh0;
        *(uint4*)&sBh[swzo(sr, sc + 1)] = bh1;
        *(uint4*)&sBl[swzo(sr, sc)]     = bl0;
        *(uint4*)&sBl[swzo(sr, sc + 1)] = bl1;
        __syncthreads();

        bf16x8 ah[4], al[4], bh[4], bl[4];
#pragma unroll
        for (int f = 0; f < 4; f++) {
            const int row = wm + f * 16 + lr;
            const int off = swzo(row, lk);
            ah[f] = *(const bf16x8*)&sAh[off];
            al[f] = *(const bf16x8*)&sAl[off];
            const int col = wn + f * 16 + lr;
            const int offb = swzo(col, lk);
            bh[f] = *(const bf16x8*)&sBh[offb];
            bl[f] = *(const bf16x8*)&sBl[offb];
        }
#pragma unroll
        for (int fm = 0; fm < 4; fm++)
#pragma unroll
            for (int fn = 0; fn < 4; fn++) {
                acc[fm][fn] = __builtin_amdgcn_mfma_f32_16x16x32_bf16(ah[fm], bh[fn], acc[fm][fn], 0, 0, 0);
                acc[fm][fn] = __builtin_amdgcn_mfma_f32_16x16x32_bf16(al[fm], bh[fn], acc[fm][fn], 0, 0, 0);
                acc[fm][fn] = __builtin_amdgcn_mfma_f32_16x16x32_bf16(ah[fm], bl[fn], acc[fm][fn], 0, 0, 0);
            }
    }
#pragma unroll
    for (int fm = 0; fm < 4; fm++) {
        const int mrow = m0 + wm + fm * 16 + lk * 4;
#pragma unroll
        for (int fn = 0; fn < 4; fn++) {
            const int col = n0 + wn + fn * 16 + lr;
            if (col < N) {
                const float bv = bias[col];
#pragma unroll
                for (int j = 0; j < 4; j++) {
                    float v = acc[fm][fn][j] + bv;
                    if (RELU) v = fmaxf(v, 0.0f);
                    C[(size_t)(mrow + j) * N + col] = v;
                }
            }
        }
    }
}

// ---------------------------------------------------------------------------
// Merged GRU GEMM: one launch computes BOTH gi = X@Wih^T+bih (blocks x<12)
// and gh = H@Whh^T+bhh (blocks x>=12). Pre-split operands, prefetched K-loop.
// N fixed 1536, M%128==0, K%32==0.
// ---------------------------------------------------------------------------
__global__ __launch_bounds__(256, 3) void gru_gemm2(
    const u16* __restrict__ Xh, const u16* __restrict__ Xl,
    const u16* __restrict__ WiH, const u16* __restrict__ WiL,
    const float* __restrict__ bi, float* __restrict__ gi,
    const u16* __restrict__ Hh, const u16* __restrict__ Hl,
    const u16* __restrict__ WhH, const u16* __restrict__ WhL,
    const float* __restrict__ bhs, float* __restrict__ gh_, int K)
{
    __shared__ u16 sAh[128 * 32], sAl[128 * 32], sBh[128 * 32], sBl[128 * 32];
    const bool isH = blockIdx.x >= 12;
    const u16* Ahi = isH ? Hh : Xh;
    const u16* Alo = isH ? Hl : Xl;
    const u16* Bhi = isH ? WhH : WiH;
    const u16* Blo = isH ? WhL : WiL;
    const float* bias = isH ? bhs : bi;
    float* C = isH ? gh_ : gi;
    const int n0 = (blockIdx.x - (isH ? 12 : 0)) * 128;
    const int m0 = blockIdx.y * 128;

    const int t = threadIdx.x;
    const int wid = t >> 6, lane = t & 63;
    const int wm = (wid >> 1) * 64, wn = (wid & 1) * 64;
    const int lr = lane & 15, lk = lane >> 4;

    f32x4 acc[4][4] = {};

    const int sr = t >> 1;
    const int sc = (t & 1) * 2;
    const u16* Ahp = Ahi + (size_t)(m0 + sr) * K + (t & 1) * 16;
    const u16* Alp = Alo + (size_t)(m0 + sr) * K + (t & 1) * 16;
    const u16* Bhp = Bhi + (size_t)(n0 + sr) * K + (t & 1) * 16;
    const u16* Blp = Blo + (size_t)(n0 + sr) * K + (t & 1) * 16;

    uint4 ah0, ah1, al0, al1, bh0, bh1, bl0, bl1;
    ah0 = *(const uint4*)(Ahp); ah1 = *(const uint4*)(Ahp + 8);
    al0 = *(const uint4*)(Alp); al1 = *(const uint4*)(Alp + 8);
    bh0 = *(const uint4*)(Bhp); bh1 = *(const uint4*)(Bhp + 8);
    bl0 = *(const uint4*)(Blp); bl1 = *(const uint4*)(Blp + 8);

    for (int k0 = 0; k0 < K; k0 += 32) {
        __syncthreads();
        *(uint4*)&sAh[swzo(sr, sc)]     = ah0;
        *(uint4*)&sAh[swzo(sr, sc + 1)] = ah1;
        *(uint4*)&sAl[swzo(sr, sc)]     = al0;
        *(uint4*)&sAl[swzo(sr, sc + 1)] = al1;
        *(uint4*)&sBh[swzo(sr, sc)]     = bh0;
        *(uint4*)&sBh[swzo(sr, sc + 1)] = bh1;
        *(uint4*)&sBl[swzo(sr, sc)]     = bl0;
        *(uint4*)&sBl[swzo(sr, sc + 1)] = bl1;
        __syncthreads();

        const int kn = k0 + 32;
        if (kn < K) {
            ah0 = *(const uint4*)(Ahp + kn); ah1 = *(const uint4*)(Ahp + kn + 8);
            al0 = *(const uint4*)(Alp + kn); al1 = *(const uint4*)(Alp + kn + 8);
            bh0 = *(const uint4*)(Bhp + kn); bh1 = *(const uint4*)(Bhp + kn + 8);
            bl0 = *(const uint4*)(Blp + kn); bl1 = *(const uint4*)(Blp + kn + 8);
        }

        bf16x8 ah[4], al[4], bh[4], bl[4];
#pragma unroll
        for (int f = 0; f < 4; f++) {
            const int row = wm + f * 16 + lr;
            const int off = swzo(row, lk);
            ah[f] = *(const bf16x8*)&sAh[off];
            al[f] = *(const bf16x8*)&sAl[off];
            const int col = wn + f * 16 + lr;
            const int offb = swzo(col, lk);
            bh[f] = *(const bf16x8*)&sBh[offb];
            bl[f] = *(const bf16x8*)&sBl[offb];
        }
#pragma unroll
        for (int fm = 0; fm < 4; fm++)
#pragma unroll
            for (int fn = 0; fn < 4; fn++) {
                acc[fm][fn] = __builtin_amdgcn_mfma_f32_16x16x32_bf16(ah[fm], bh[fn], acc[fm][fn], 0, 0, 0);
                acc[fm][fn] = __builtin_amdgcn_mfma_f32_16x16x32_bf16(al[fm], bh[fn], acc[fm][fn], 0, 0, 0);
                acc[fm][fn] = __builtin_amdgcn_mfma_f32_16x16x32_bf16(ah[fm], bl[fn], acc[fm][fn], 0, 0, 0);
            }
    }
#pragma unroll
    for (int fm = 0; fm < 4; fm++) {
        const int mrow = m0 + wm + fm * 16 + lk * 4;
#pragma unroll
        for (int fn = 0; fn < 4; fn++) {
            const int col = n0 + wn + fn * 16 + lr;
            const float bv = bias[col];
#pragma unroll
            for (int j = 0; j < 4; j++)
                C[(size_t)(mrow + j) * 1536 + col] = acc[fm][fn][j] + bv;
        }
    }
}

// ---------------------------------------------------------------------------
// GRU pointwise combine: gi/gh are [R x 1536] (r,z,n panels), H/Hout [R x 512]
// In-place safe (Hout may alias H).
// ---------------------------------------------------------------------------
__global__ __launch_bounds__(256) void gru_combine(
    const float* __restrict__ gi, const float* __restrict__ gh,
    const float* __restrict__ H, float* __restrict__ Hout, int R)
{
    const int idx = blockIdx.x * 256 + threadIdx.x;      // over R*128 float4s
    if (idx >= R * 128) return;
    const int r = idx >> 7, c4 = (idx & 127) * 4;
    const size_t gb = (size_t)r * 1536 + c4;
    const float4 ir4 = *(const float4*)&gi[gb];
    const float4 iz4 = *(const float4*)&gi[gb + 512];
    const float4 in4 = *(const float4*)&gi[gb + 1024];
    const float4 hr4 = *(const float4*)&gh[gb];
    const float4 hz4 = *(const float4*)&gh[gb + 512];
    const float4 hn4 = *(const float4*)&gh[gb + 1024];
    const float4 h4  = *(const float4*)&H[(size_t)r * 512 + c4];
    float4 o;
    {
        const float rr = sigmoidf_(ir4.x + hr4.x), zz = sigmoidf_(iz4.x + hz4.x);
        o.x = (1.0f - zz) * tanhf(in4.x + rr * hn4.x) + zz * h4.x;
    }
    {
        const float rr = sigmoidf_(ir4.y + hr4.y), zz = sigmoidf_(iz4.y + hz4.y);
        o.y = (1.0f - zz) * tanhf(in4.y + rr * hn4.y) + zz * h4.y;
    }
    {
        const float rr = sigmoidf_(ir4.z + hr4.z), zz = sigmoidf_(iz4.z + hz4.z);
        o.z = (1.0f - zz) * tanhf(in4.z + rr * hn4.z) + zz * h4.z;
    }
    {
        const float rr = sigmoidf_(ir4.w + hr4.w), zz = sigmoidf_(iz4.w + hz4.w);
        o.w = (1.0f - zz) * tanhf(in4.w + rr * hn4.w) + zz * h4.w;
    }
    *(float4*)&Hout[(size_t)r * 512 + c4] = o;
}

// ---------------------------------------------------------------------------
__global__ __launch_bounds__(256) void count_kernel(const int* __restrict__ rel,
                                                    float* cnt_s, float* cnt_o)
{
    const int e = blockIdx.x * 256 + threadIdx.x;
    atomicAdd(&cnt_s[rel[2 * e]], 1.0f);
    atomicAdd(&cnt_o[rel[2 * e + 1]], 1.0f);
}

// ---------------------------------------------------------------------------
// Fused gates + message pass: one block (256 thr) per edge.
// Computes 4 scalar gates (block reduce over 512-elem dots), then scatters
// pre-scaled node messages and writes edge messages. Each thread owns 2 cols.
// ---------------------------------------------------------------------------
__global__ __launch_bounds__(256) void gatepass(
    const float* __restrict__ h_obj, const float* __restrict__ h_edge,
    const int* __restrict__ rel,
    const float* __restrict__ wsn, const float* __restrict__ bsn,
    const float* __restrict__ won, const float* __restrict__ bon,
    const float* __restrict__ wse, const float* __restrict__ bse,
    const float* __restrict__ woe, const float* __restrict__ boe,
    const float* __restrict__ cnt_s, const float* __restrict__ cnt_o,
    float* __restrict__ nm, float* __restrict__ em)
{
    __shared__ float red[4][4];
    const int e = blockIdx.x;
    const int t = threadIdx.x;
    const int wid = t >> 6, lane = t & 63;
    const int s = rel[2 * e], o = rel[2 * e + 1];
    const int c = 2 * t;

    const float2 hs = *(const float2*)&h_obj[(size_t)s * DIM + c];
    const float2 ho = *(const float2*)&h_obj[(size_t)o * DIM + c];
    const float2 he = *(const float2*)&h_edge[(size_t)e * DIM + c];

    const float2 w0v = *(const float2*)&wsn[c], w0e = *(const float2*)&wsn[DIM + c];
    const float2 w1v = *(const float2*)&won[c], w1e = *(const float2*)&won[DIM + c];
    const float2 w2v = *(const float2*)&wse[c], w2e = *(const float2*)&wse[DIM + c];
    const float2 w3v = *(const float2*)&woe[c], w3e = *(const float2*)&woe[DIM + c];

    float p0 = hs.x * w0v.x + hs.y * w0v.y + he.x * w0e.x + he.y * w0e.y;
    float p1 = ho.x * w1v.x + ho.y * w1v.y + he.x * w1e.x + he.y * w1e.y;
    float p2 = hs.x * w2v.x + hs.y * w2v.y + he.x * w2e.x + he.y * w2e.y;
    float p3 = ho.x * w3v.x + ho.y * w3v.y + he.x * w3e.x + he.y * w3e.y;

#pragma unroll
    for (int off = 32; off; off >>= 1) {
        p0 += __shfl_xor(p0, off);
        p1 += __shfl_xor(p1, off);
        p2 += __shfl_xor(p2, off);
        p3 += __shfl_xor(p3, off);
    }
    if (lane == 0) { red[wid][0] = p0; red[wid][1] = p1; red[wid][2] = p2; red[wid][3] = p3; }
    __syncthreads();
    const float gsn = sigmoidf_(red[0][0] + red[1][0] + red[2][0] + red[3][0] + bsn[0]);
    const float gon = sigmoidf_(red[0][1] + red[1][1] + red[2][1] + red[3][1] + bon[0]);
    const float gse = sigmoidf_(red[0][2] + red[1][2] + red[2][2] + red[3][2] + bse[0]);
    const float goe = sigmoidf_(red[0][3] + red[1][3] + red[2][3] + red[3][3] + boe[0]);

    const float as = 0.5f * gsn / (cnt_s[s] + EPSV);
    const float ao = 0.5f * gon / (cnt_o[o] + EPSV);

    atomicAdd(&nm[(size_t)s * DIM + c],     as * he.x);
    atomicAdd(&nm[(size_t)s * DIM + c + 1], as * he.y);
    atomicAdd(&nm[(size_t)o * DIM + c],     ao * he.x);
    atomicAdd(&nm[(size_t)o * DIM + c + 1], ao * he.y);
    float2 emv;
    emv.x = 0.5f * (gse * hs.x + goe * ho.x);
    emv.y = 0.5f * (gse * hs.y + goe * ho.y);
    *(float2*)&em[(size_t)e * DIM + c] = emv;
}

__global__ __launch_bounds__(256) void argmax_kernel(const float* __restrict__ logits,
                                                     float* __restrict__ out)
{
    const int row = blockIdx.x * 4 + (threadIdx.x >> 6);
    const int lane = threadIdx.x & 63;
    float bv = -1e30f; int bi = 1;
    for (int j = 1 + lane; j < N_OBJ_CLS; j += 64) {
        const float v = logits[(size_t)row * N_OBJ_CLS + j];
        if (v > bv) { bv = v; bi = j; }
    }
#pragma unroll
    for (int off = 32; off; off >>= 1) {
        const float ov = __shfl_xor(bv, off);
        const int oi = __shfl_xor(bi, off);
        if (ov > bv || (ov == bv && oi < bi)) { bv = ov; bi = oi; }
    }
    if (lane == 0) out[row] = (float)bi;
}

__global__ __launch_bounds__(256) void relinds_kernel(const int* __restrict__ rel,
                                                      float* __restrict__ out)
{
    const int i = blockIdx.x * 256 + threadIdx.x;
    out[i] = (float)rel[i];
}

// ---------------------------------------------------------------------------
extern "C" void kernel_launch(void* const* d_in, const int* in_sizes, int n_in,
                              void* d_out, int out_size, void* d_ws, size_t ws_size,
                              hipStream_t stream)
{
    const float* x_obj = (const float*)d_in[0];
    const float* x_pred = (const float*)d_in[1];
    const int* rel = (const int*)d_in[2];
    const float* oe_w1 = (const float*)d_in[3];
    const float* oe_b1 = (const float*)d_in[4];
    const float* oe_w2 = (const float*)d_in[5];
    const float* oe_b2 = (const float*)d_in[6];
    const float* pe_w1 = (const float*)d_in[7];
    const float* pe_b1 = (const float*)d_in[8];
    const float* pe_w2 = (const float*)d_in[9];
    const float* pe_b2 = (const float*)d_in[10];
    const float* g_sn_w = (const float*)d_in[11];
    const float* g_sn_b = (const float*)d_in[12];
    const float* g_on_w = (const float*)d_in[13];
    const float* g_on_b = (const float*)d_in[14];
    const float* g_se_w = (const float*)d_in[15];
    const float* g_se_b = (const float*)d_in[16];
    const float* g_oe_w = (const float*)d_in[17];
    const float* g_oe_b = (const float*)d_in[18];
    const float* ngru_wih = (const float*)d_in[19];
    const float* ngru_whh = (const float*)d_in[20];
    const float* ngru_bih = (const float*)d_in[21];
    const float* ngru_bhh = (const float*)d_in[22];
    const float* egru_wih = (const float*)d_in[23];
    const float* egru_whh = (const float*)d_in[24];
    const float* egru_bih = (const float*)d_in[25];
    const float* egru_bhh = (const float*)d_in[26];
    const float* op_w = (const float*)d_in[27];
    const float* op_b = (const float*)d_in[28];
    const float* pp_w = (const float*)d_in[29];
    const float* pp_b = (const float*)d_in[30];

    float* out = (float*)d_out;
    float* ws = (float*)d_ws;

    float* h_obj = out + OFF_HOBJ;       // in-place GRU state in d_out
    float* h_edge = out + OFF_HEDGE;

    // workspace layout
    float* tmp_e = ws;                                  // 32768*512 (enc hidden / em)
    float* tmp_o = tmp_e + (size_t)N_RELS * DIM;        // 2048*512 (enc hidden / nm)
    float* cnts = tmp_o + (size_t)N_OBJS * DIM;         // 2*N_OBJS
    float* cnt_s = cnts;
    float* cnt_o = cnts + N_OBJS;
    float* em = tmp_e;
    float* nm = tmp_o;

    // split-weight area (u16)
    u16* wp = (u16*)(cnts + 2 * N_OBJS);
    const int s_big = DIM * D_IN, s_sq = DIM * DIM, s_gru = 3 * DIM * DIM;
    const int s_op = N_OBJ_CLS * DIM, s_pp = N_REL_CLS * DIM;
    u16 *oe1h = wp; wp += s_big; u16 *oe1l = wp; wp += s_big;
    u16 *pe1h = wp; wp += s_big; u16 *pe1l = wp; wp += s_big;
    u16 *oe2h = wp; wp += s_sq;  u16 *oe2l = wp; wp += s_sq;
    u16 *pe2h = wp; wp += s_sq;  u16 *pe2l = wp; wp += s_sq;
    u16 *nih_h = wp; wp += s_gru; u16 *nih_l = wp; wp += s_gru;
    u16 *nhh_h = wp; wp += s_gru; u16 *nhh_l = wp; wp += s_gru;
    u16 *eih_h = wp; wp += s_gru; u16 *eih_l = wp; wp += s_gru;
    u16 *ehh_h = wp; wp += s_gru; u16 *ehh_l = wp; wp += s_gru;
    u16 *oph = wp; wp += s_op;   u16 *opl = wp; wp += s_op;
    u16 *pph = wp; wp += s_pp;   u16 *ppl = wp; wp += s_pp;

    // GRU chunk buffers (dynamic R based on ws_size): splits (4 x R*512 u16)
    // + gi/gh (2 x R*1536 f32)  => 16384 bytes per row
    const size_t used = (size_t)((char*)wp - (char*)ws);
    int R = 2048;
    if (used + (size_t)8192 * 16384 <= ws_size) R = 8192;
    else if (used + (size_t)4096 * 16384 <= ws_size) R = 4096;
    u16* cxh = wp;
    u16* cxl = cxh + (size_t)R * DIM;
    u16* chh = cxl + (size_t)R * DIM;
    u16* chl = chh + (size_t)R * DIM;
    float* gi = (float*)(chl + (size_t)R * DIM);
    float* gh = gi + (size_t)R * 1536;

    auto cvt = [&](const float* s, u16* h, u16* l, int n) {
        convert_split<<<(n / 4 + 255) / 256, 256, 0, stream>>>(s, h, l, n / 4);
    };
    cvt(oe_w1, oe1h, oe1l, s_big);
    cvt(pe_w1, pe1h, pe1l, s_big);
    cvt(oe_w2, oe2h, oe2l, s_sq);
    cvt(pe_w2, pe2h, pe2l, s_sq);
    cvt(ngru_wih, nih_h, nih_l, s_gru);
    cvt(ngru_whh, nhh_h, nhh_l, s_gru);
    cvt(egru_wih, eih_h, eih_l, s_gru);
    cvt(egru_whh, ehh_h, ehh_l, s_gru);
    cvt(op_w, oph, opl, s_op);
    cvt(pp_w, pph, ppl, s_pp);

    // degree counts
    hipMemsetAsync(cnts, 0, 2 * N_OBJS * sizeof(float), stream);
    count_kernel<<<N_RELS / 256, 256, 0, stream>>>(rel, cnt_s, cnt_o);

    // encoders (enc2 writes h directly into d_out; GRU updates in place)
    gemm_split<true><<<dim3(DIM / 128, N_OBJS / 128), 256, 0, stream>>>(
        x_obj, oe1h, oe1l, oe_b1, tmp_o, N_OBJS, DIM, D_IN);
    gemm_split<false><<<dim3(DIM / 128, N_OBJS / 128), 256, 0, stream>>>(
        tmp_o, oe2h, oe2l, oe_b2, h_obj, N_OBJS, DIM, DIM);
    gemm_split<true><<<dim3(DIM / 128, N_RELS / 128), 256, 0, stream>>>(
        x_pred, pe1h, pe1l, pe_b1, tmp_e, N_RELS, DIM, D_IN);
    gemm_split<false><<<dim3(DIM / 128, N_RELS / 128), 256, 0, stream>>>(
        tmp_e, pe2h, pe2l, pe_b2, h_edge, N_RELS, DIM, DIM);

    // chunked two-pass GRU, in-place on H
    auto run_gru = [&](const float* X, float* H,
                       const u16* WiH, const u16* WiL, const u16* WhH, const u16* WhL,
                       const float* bih, const float* bhh, int Mtot) {
        for (int r0 = 0; r0 < Mtot; r0 += R) {
            const int Rc = (Mtot - r0 < R) ? (Mtot - r0) : R;
            cvt(X + (size_t)r0 * DIM, cxh, cxl, Rc * DIM);
            cvt(H + (size_t)r0 * DIM, chh, chl, Rc * DIM);
            gru_gemm2<<<dim3(24, Rc / 128), 256, 0, stream>>>(
                cxh, cxl, WiH, WiL, bih, gi,
                chh, chl, WhH, WhL, bhh, gh, DIM);
            gru_combine<<<(Rc * 128 + 255) / 256, 256, 0, stream>>>(
                gi, gh, H + (size_t)r0 * DIM, H + (size_t)r0 * DIM, Rc);
        }
    };

    // message-passing steps (in-place state in d_out)
    for (int step = 0; step < 2; step++) {
        hipMemsetAsync(nm, 0, (size_t)N_OBJS * DIM * sizeof(float), stream);
        gatepass<<<N_RELS, 256, 0, stream>>>(
            h_obj, h_edge, rel,
            g_sn_w, g_sn_b, g_on_w, g_on_b, g_se_w, g_se_b, g_oe_w, g_oe_b,
            cnt_s, cnt_o, nm, em);
        run_gru(nm, h_obj, nih_h, nih_l, nhh_h, nhh_l, ngru_bih, ngru_bhh, N_OBJS);
        run_gru(em, h_edge, eih_h, eih_l, ehh_h, ehh_l, egru_bih, egru_bhh, N_RELS);
    }

    // classifiers
    gemm_split<false><<<dim3((N_OBJ_CLS + 127) / 128, N_OBJS / 128), 256, 0, stream>>>(
        h_obj, oph, opl, op_b, out + OFF_OLOG, N_OBJS, N_OBJ_CLS, DIM);
    gemm_split<false><<<dim3((N_REL_CLS + 127) / 128, N_RELS / 128), 256, 0, stream>>>(
        h_edge, pph, ppl, pp_b, out + OFF_PLOG, N_RELS, N_REL_CLS, DIM);

    // labels + rel_inds passthrough
    argmax_kernel<<<N_OBJS / 4, 256, 0, stream>>>(out + OFF_OLOG, out + OFF_LBL);
    relinds_kernel<<<(2 * N_RELS) / 256, 256, 0, stream>>>(rel, out + OFF_RI);
}

// Round 5
// 1950.058 us; speedup vs baseline: 1.2820x; 1.2820x over previous
//
#include <hip/hip_runtime.h>
#include <math.h>

typedef unsigned short u16;
typedef unsigned int u32;
typedef _Float16 f16;
typedef f16 f16x8 __attribute__((ext_vector_type(8)));
typedef float f32x4 __attribute__((ext_vector_type(4)));

#define DIM 512
#define D_IN 4096
#define N_OBJS 2048
#define N_RELS 32768
#define N_OBJ_CLS 151
#define N_REL_CLS 51
#define EPSV 1e-5f

// d_out layout (floats)
#define OFF_HOBJ  0
#define OFF_HEDGE (N_OBJS*DIM)
#define OFF_OLOG  (OFF_HEDGE + N_RELS*DIM)
#define OFF_PLOG  (OFF_OLOG + N_OBJS*N_OBJ_CLS)
#define OFF_LBL   (OFF_PLOG + N_RELS*N_REL_CLS)
#define OFF_RI    (OFF_LBL + N_OBJS)

__device__ __forceinline__ float sigmoidf_(float x) { return 1.0f / (1.0f + expf(-x)); }
__device__ __forceinline__ u16 f2h_(float f) {
    union { f16 h; u16 u; } c; c.h = (f16)f; return c.u;
}
__device__ __forceinline__ float h2f_(u16 u) {
    union { f16 h; u16 u; } c; c.u = u; return (float)c.h;
}

// 8 fp32 -> packed f16 hi (uint4) + f16 lo (uint4); a ~= hi + lo to 2^-24
__device__ __forceinline__ void cvt8h(const float* f, uint4& h, uint4& l) {
    u32 hh[8], ll[8];
#pragma unroll
    for (int i = 0; i < 8; i++) {
        u16 x = f2h_(f[i]);
        hh[i] = x;
        ll[i] = f2h_(f[i] - h2f_(x));
    }
    h.x = hh[0] | (hh[1] << 16); h.y = hh[2] | (hh[3] << 16);
    h.z = hh[4] | (hh[5] << 16); h.w = hh[6] | (hh[7] << 16);
    l.x = ll[0] | (ll[1] << 16); l.y = ll[2] | (ll[3] << 16);
    l.z = ll[4] | (ll[5] << 16); l.w = ll[6] | (ll[7] << 16);
}

// LDS offset (u16 units) for (row, chunk8) in a [rows][32] tile, XOR-swizzled
__device__ __forceinline__ int swzo(int row, int c) {
    return row * 32 + ((c ^ ((row >> 1) & 3)) << 3);
}

// async global->LDS, 16B per lane; LDS dest = wave-uniform base + lane*16
__device__ __forceinline__ void gload16(const void* g, void* l) {
    __builtin_amdgcn_global_load_lds(
        (const __attribute__((address_space(1))) void*)g,
        (__attribute__((address_space(3))) void*)l, 16, 0, 0);
}

// ---------------------------------------------------------------------------
// weights: fp32 -> f16 hi only
__global__ __launch_bounds__(256) void convert_h(const float* __restrict__ src,
    u16* __restrict__ hi, int n4)
{
    const int i = blockIdx.x * 256 + threadIdx.x;
    if (i >= n4) return;
    const float4 v = ((const float4*)src)[i];
    ((ushort4*)hi)[i] = make_ushort4(f2h_(v.x), f2h_(v.y), f2h_(v.z), f2h_(v.w));
}

// activations: fp32 -> f16 hi + lo
__global__ __launch_bounds__(256) void convert_hl(const float* __restrict__ src,
    u16* __restrict__ hi, u16* __restrict__ lo, int n4)
{
    const int i = blockIdx.x * 256 + threadIdx.x;
    if (i >= n4) return;
    const float4 v = ((const float4*)src)[i];
    u16 h0 = f2h_(v.x), h1 = f2h_(v.y), h2 = f2h_(v.z), h3 = f2h_(v.w);
    ((ushort4*)hi)[i] = make_ushort4(h0, h1, h2, h3);
    ((ushort4*)lo)[i] = make_ushort4(f2h_(v.x - h2f_(h0)), f2h_(v.y - h2f_(h1)),
                                     f2h_(v.z - h2f_(h2)), f2h_(v.w - h2f_(h3)));
}

// ---------------------------------------------------------------------------
// 2-term f16 GEMM, fp32 A split on the fly, B f16-hi via global_load_lds:
// C = act(A @ Bh^T + bias).  128x128 tile, 4 waves, BK=32, 16x16x32 f16 MFMA.
// M%128==0, K%32==0; B rows must be readable up to n0+128 (pad allocs).
// ---------------------------------------------------------------------------
template<bool RELU>
__global__ __launch_bounds__(256, 2) void gemm_split(
    const float* __restrict__ A, const u16* __restrict__ Bhi,
    const float* __restrict__ bias, float* __restrict__ C, int M, int N, int K)
{
    __shared__ u16 sAh[128 * 32], sAl[128 * 32], sBh[128 * 32];
    const int t = threadIdx.x;
    const int m0 = blockIdx.y * 128, n0 = blockIdx.x * 128;
    const int wid = t >> 6, lane = t & 63;
    const int wm = (wid >> 1) * 64, wn = (wid & 1) * 64;
    const int lr = lane & 15, lk = lane >> 4;

    f32x4 acc[4][4] = {};

    const int sr = t >> 1;
    const int sc = (t & 1) * 2;
    const float* Ap = A + (size_t)(m0 + sr) * K + (t & 1) * 16;

    // per-lane pre-swizzled global source for B staging (linear LDS dest)
    const int rB = (wid * 2) * 16 + (lane >> 2);
    const int cB = (lane & 3) ^ ((rB >> 1) & 3);
    const u16* Bp0 = Bhi + (size_t)(n0 + rB) * K + cB * 8;
    const u16* Bp1 = Bp0 + (size_t)16 * K;
    u16* Bd0 = &sBh[(wid * 2) * 512];
    u16* Bd1 = Bd0 + 512;

    for (int k0 = 0; k0 < K; k0 += 32) {
        float fv[16];
        *(float4*)&fv[0]  = *(const float4*)(Ap + k0);
        *(float4*)&fv[4]  = *(const float4*)(Ap + k0 + 4);
        *(float4*)&fv[8]  = *(const float4*)(Ap + k0 + 8);
        *(float4*)&fv[12] = *(const float4*)(Ap + k0 + 12);
        uint4 ah0, ah1, al0, al1;
        cvt8h(fv, ah0, al0); cvt8h(fv + 8, ah1, al1);

        __syncthreads();                       // previous reads complete
        gload16(Bp0 + k0, Bd0);
        gload16(Bp1 + k0, Bd1);
        *(uint4*)&sAh[swzo(sr, sc)]     = ah0;
        *(uint4*)&sAh[swzo(sr, sc + 1)] = ah1;
        *(uint4*)&sAl[swzo(sr, sc)]     = al0;
        *(uint4*)&sAl[swzo(sr, sc + 1)] = al1;
        asm volatile("s_waitcnt vmcnt(0)" ::: "memory");
        __syncthreads();

        f16x8 ah[4], al[4], bh[4];
#pragma unroll
        for (int f = 0; f < 4; f++) {
            const int off = swzo(wm + f * 16 + lr, lk);
            ah[f] = *(const f16x8*)&sAh[off];
            al[f] = *(const f16x8*)&sAl[off];
            bh[f] = *(const f16x8*)&sBh[swzo(wn + f * 16 + lr, lk)];
        }
#pragma unroll
        for (int fm = 0; fm < 4; fm++)
#pragma unroll
            for (int fn = 0; fn < 4; fn++) {
                acc[fm][fn] = __builtin_amdgcn_mfma_f32_16x16x32_f16(ah[fm], bh[fn], acc[fm][fn], 0, 0, 0);
                acc[fm][fn] = __builtin_amdgcn_mfma_f32_16x16x32_f16(al[fm], bh[fn], acc[fm][fn], 0, 0, 0);
            }
    }
#pragma unroll
    for (int fm = 0; fm < 4; fm++) {
        const int mrow = m0 + wm + fm * 16 + lk * 4;
#pragma unroll
        for (int fn = 0; fn < 4; fn++) {
            const int col = n0 + wn + fn * 16 + lr;
            if (col < N) {
                const float bv = bias[col];
#pragma unroll
                for (int j = 0; j < 4; j++) {
                    float v = acc[fm][fn][j] + bv;
                    if (RELU) v = fmaxf(v, 0.0f);
                    C[(size_t)(mrow + j) * N + col] = v;
                }
            }
        }
    }
}

// ---------------------------------------------------------------------------
// Merged GRU GEMM (2-term f16, all operands presplit, global_load_lds both
// sides): blocks x<12 -> gi = X@Wih^T+bih; x>=12 -> gh = H@Whh^T+bhh.
// Output stored as f16 (u16). N fixed 1536, M%128==0, K%32==0.
// ---------------------------------------------------------------------------
__global__ __launch_bounds__(256, 3) void gru_gemm2(
    const u16* __restrict__ Xh, const u16* __restrict__ Xl,
    const u16* __restrict__ WiH, const float* __restrict__ bi, u16* __restrict__ gi,
    const u16* __restrict__ Hh, const u16* __restrict__ Hl,
    const u16* __restrict__ WhH, const float* __restrict__ bhs, u16* __restrict__ gh_,
    int K)
{
    __shared__ u16 sAh[128 * 32], sAl[128 * 32], sBh[128 * 32];
    const bool isH = blockIdx.x >= 12;
    const u16* Ahi = isH ? Hh : Xh;
    const u16* Alo = isH ? Hl : Xl;
    const u16* Bhi = isH ? WhH : WiH;
    const float* bias = isH ? bhs : bi;
    u16* C = isH ? gh_ : gi;
    const int n0 = (blockIdx.x - (isH ? 12 : 0)) * 128;
    const int m0 = blockIdx.y * 128;

    const int t = threadIdx.x;
    const int wid = t >> 6, lane = t & 63;
    const int wm = (wid >> 1) * 64, wn = (wid & 1) * 64;
    const int lr = lane & 15, lk = lane >> 4;

    f32x4 acc[4][4] = {};

    // per-lane pre-swizzled global sources, linear LDS dests
    const int rr = (wid * 2) * 16 + (lane >> 2);
    const int cc = (lane & 3) ^ ((rr >> 1) & 3);
    const size_t aoff = (size_t)(m0 + rr) * K + cc * 8;
    const size_t boff = (size_t)(n0 + rr) * K + cc * 8;
    const u16* pAh0 = Ahi + aoff; const u16* pAh1 = pAh0 + (size_t)16 * K;
    const u16* pAl0 = Alo + aoff; const u16* pAl1 = pAl0 + (size_t)16 * K;
    const u16* pB0 = Bhi + boff;  const u16* pB1 = pB0 + (size_t)16 * K;
    u16* dAh0 = &sAh[(wid * 2) * 512]; u16* dAh1 = dAh0 + 512;
    u16* dAl0 = &sAl[(wid * 2) * 512]; u16* dAl1 = dAl0 + 512;
    u16* dB0  = &sBh[(wid * 2) * 512]; u16* dB1  = dB0 + 512;

    for (int k0 = 0; k0 < K; k0 += 32) {
        __syncthreads();
        gload16(pAh0 + k0, dAh0); gload16(pAh1 + k0, dAh1);
        gload16(pAl0 + k0, dAl0); gload16(pAl1 + k0, dAl1);
        gload16(pB0 + k0, dB0);   gload16(pB1 + k0, dB1);
        asm volatile("s_waitcnt vmcnt(0)" ::: "memory");
        __syncthreads();

        f16x8 ah[4], al[4], bh[4];
#pragma unroll
        for (int f = 0; f < 4; f++) {
            const int off = swzo(wm + f * 16 + lr, lk);
            ah[f] = *(const f16x8*)&sAh[off];
            al[f] = *(const f16x8*)&sAl[off];
            bh[f] = *(const f16x8*)&sBh[swzo(wn + f * 16 + lr, lk)];
        }
#pragma unroll
        for (int fm = 0; fm < 4; fm++)
#pragma unroll
            for (int fn = 0; fn < 4; fn++) {
                acc[fm][fn] = __builtin_amdgcn_mfma_f32_16x16x32_f16(ah[fm], bh[fn], acc[fm][fn], 0, 0, 0);
                acc[fm][fn] = __builtin_amdgcn_mfma_f32_16x16x32_f16(al[fm], bh[fn], acc[fm][fn], 0, 0, 0);
            }
    }
#pragma unroll
    for (int fm = 0; fm < 4; fm++) {
        const int mrow = m0 + wm + fm * 16 + lk * 4;
#pragma unroll
        for (int fn = 0; fn < 4; fn++) {
            const int col = n0 + wn + fn * 16 + lr;
            const float bv = bias[col];
#pragma unroll
            for (int j = 0; j < 4; j++)
                C[(size_t)(mrow + j) * 1536 + col] = f2h_(acc[fm][fn][j] + bv);
        }
    }
}

// ---------------------------------------------------------------------------
// GRU pointwise combine: gi/gh f16 [R x 1536] (r,z,n), H/Hout f32 [R x 512]
// ---------------------------------------------------------------------------
__device__ __forceinline__ float gcomb(u16 ir, u16 iz, u16 in_, u16 hr, u16 hz,
                                       u16 hn, float h) {
    const float r = sigmoidf_(h2f_(ir) + h2f_(hr));
    const float z = sigmoidf_(h2f_(iz) + h2f_(hz));
    const float n = tanhf(h2f_(in_) + r * h2f_(hn));
    return (1.0f - z) * n + z * h;
}

__global__ __launch_bounds__(256) void gru_combine(
    const u16* __restrict__ gi, const u16* __restrict__ gh,
    const float* __restrict__ H, float* __restrict__ Hout, int R)
{
    const int idx = blockIdx.x * 256 + threadIdx.x;      // R*128 quads
    if (idx >= R * 128) return;
    const int r = idx >> 7, c4 = (idx & 127) * 4;
    const size_t gb = (size_t)r * 1536 + c4;
    const ushort4 ir4 = *(const ushort4*)&gi[gb];
    const ushort4 iz4 = *(const ushort4*)&gi[gb + 512];
    const ushort4 in4 = *(const ushort4*)&gi[gb + 1024];
    const ushort4 hr4 = *(const ushort4*)&gh[gb];
    const ushort4 hz4 = *(const ushort4*)&gh[gb + 512];
    const ushort4 hn4 = *(const ushort4*)&gh[gb + 1024];
    const float4 h4 = *(const float4*)&H[(size_t)r * 512 + c4];
    float4 o;
    o.x = gcomb(ir4.x, iz4.x, in4.x, hr4.x, hz4.x, hn4.x, h4.x);
    o.y = gcomb(ir4.y, iz4.y, in4.y, hr4.y, hz4.y, hn4.y, h4.y);
    o.z = gcomb(ir4.z, iz4.z, in4.z, hr4.z, hz4.z, hn4.z, h4.z);
    o.w = gcomb(ir4.w, iz4.w, in4.w, hr4.w, hz4.w, hn4.w, h4.w);
    *(float4*)&Hout[(size_t)r * 512 + c4] = o;
}

// ---------------------------------------------------------------------------
__global__ __launch_bounds__(256) void count_kernel(const int* __restrict__ rel,
                                                    float* cnt_s, float* cnt_o)
{
    const int e = blockIdx.x * 256 + threadIdx.x;
    atomicAdd(&cnt_s[rel[2 * e]], 1.0f);
    atomicAdd(&cnt_o[rel[2 * e + 1]], 1.0f);
}

// ---------------------------------------------------------------------------
// Fused gates + message pass: one block (256 thr) per edge.
// ---------------------------------------------------------------------------
__global__ __launch_bounds__(256) void gatepass(
    const float* __restrict__ h_obj, const float* __restrict__ h_edge,
    const int* __restrict__ rel,
    const float* __restrict__ wsn, const float* __restrict__ bsn,
    const float* __restrict__ won, const float* __restrict__ bon,
    const float* __restrict__ wse, const float* __restrict__ bse,
    const float* __restrict__ woe, const float* __restrict__ boe,
    const float* __restrict__ cnt_s, const float* __restrict__ cnt_o,
    float* __restrict__ nm, float* __restrict__ em)
{
    __shared__ float red[4][4];
    const int e = blockIdx.x;
    const int t = threadIdx.x;
    const int wid = t >> 6, lane = t & 63;
    const int s = rel[2 * e], o = rel[2 * e + 1];
    const int c = 2 * t;

    const float2 hs = *(const float2*)&h_obj[(size_t)s * DIM + c];
    const float2 ho = *(const float2*)&h_obj[(size_t)o * DIM + c];
    const float2 he = *(const float2*)&h_edge[(size_t)e * DIM + c];

    const float2 w0v = *(const float2*)&wsn[c], w0e = *(const float2*)&wsn[DIM + c];
    const float2 w1v = *(const float2*)&won[c], w1e = *(const float2*)&won[DIM + c];
    const float2 w2v = *(const float2*)&wse[c], w2e = *(const float2*)&wse[DIM + c];
    const float2 w3v = *(const float2*)&woe[c], w3e = *(const float2*)&woe[DIM + c];

    float p0 = hs.x * w0v.x + hs.y * w0v.y + he.x * w0e.x + he.y * w0e.y;
    float p1 = ho.x * w1v.x + ho.y * w1v.y + he.x * w1e.x + he.y * w1e.y;
    float p2 = hs.x * w2v.x + hs.y * w2v.y + he.x * w2e.x + he.y * w2e.y;
    float p3 = ho.x * w3v.x + ho.y * w3v.y + he.x * w3e.x + he.y * w3e.y;

#pragma unroll
    for (int off = 32; off; off >>= 1) {
        p0 += __shfl_xor(p0, off);
        p1 += __shfl_xor(p1, off);
        p2 += __shfl_xor(p2, off);
        p3 += __shfl_xor(p3, off);
    }
    if (lane == 0) { red[wid][0] = p0; red[wid][1] = p1; red[wid][2] = p2; red[wid][3] = p3; }
    __syncthreads();
    const float gsn = sigmoidf_(red[0][0] + red[1][0] + red[2][0] + red[3][0] + bsn[0]);
    const float gon = sigmoidf_(red[0][1] + red[1][1] + red[2][1] + red[3][1] + bon[0]);
    const float gse = sigmoidf_(red[0][2] + red[1][2] + red[2][2] + red[3][2] + bse[0]);
    const float goe = sigmoidf_(red[0][3] + red[1][3] + red[2][3] + red[3][3] + boe[0]);

    const float as = 0.5f * gsn / (cnt_s[s] + EPSV);
    const float ao = 0.5f * gon / (cnt_o[o] + EPSV);

    atomicAdd(&nm[(size_t)s * DIM + c],     as * he.x);
    atomicAdd(&nm[(size_t)s * DIM + c + 1], as * he.y);
    atomicAdd(&nm[(size_t)o * DIM + c],     ao * he.x);
    atomicAdd(&nm[(size_t)o * DIM + c + 1], ao * he.y);
    float2 emv;
    emv.x = 0.5f * (gse * hs.x + goe * ho.x);
    emv.y = 0.5f * (gse * hs.y + goe * ho.y);
    *(float2*)&em[(size_t)e * DIM + c] = emv;
}

__global__ __launch_bounds__(256) void argmax_kernel(const float* __restrict__ logits,
                                                     float* __restrict__ out)
{
    const int row = blockIdx.x * 4 + (threadIdx.x >> 6);
    const int lane = threadIdx.x & 63;
    float bv = -1e30f; int bi = 1;
    for (int j = 1 + lane; j < N_OBJ_CLS; j += 64) {
        const float v = logits[(size_t)row * N_OBJ_CLS + j];
        if (v > bv) { bv = v; bi = j; }
    }
#pragma unroll
    for (int off = 32; off; off >>= 1) {
        const float ov = __shfl_xor(bv, off);
        const int oi = __shfl_xor(bi, off);
        if (ov > bv || (ov == bv && oi < bi)) { bv = ov; bi = oi; }
    }
    if (lane == 0) out[row] = (float)bi;
}

__global__ __launch_bounds__(256) void relinds_kernel(const int* __restrict__ rel,
                                                      float* __restrict__ out)
{
    const int i = blockIdx.x * 256 + threadIdx.x;
    out[i] = (float)rel[i];
}

// ---------------------------------------------------------------------------
extern "C" void kernel_launch(void* const* d_in, const int* in_sizes, int n_in,
                              void* d_out, int out_size, void* d_ws, size_t ws_size,
                              hipStream_t stream)
{
    const float* x_obj = (const float*)d_in[0];
    const float* x_pred = (const float*)d_in[1];
    const int* rel = (const int*)d_in[2];
    const float* oe_w1 = (const float*)d_in[3];
    const float* oe_b1 = (const float*)d_in[4];
    const float* oe_w2 = (const float*)d_in[5];
    const float* oe_b2 = (const float*)d_in[6];
    const float* pe_w1 = (const float*)d_in[7];
    const float* pe_b1 = (const float*)d_in[8];
    const float* pe_w2 = (const float*)d_in[9];
    const float* pe_b2 = (const float*)d_in[10];
    const float* g_sn_w = (const float*)d_in[11];
    const float* g_sn_b = (const float*)d_in[12];
    const float* g_on_w = (const float*)d_in[13];
    const float* g_on_b = (const float*)d_in[14];
    const float* g_se_w = (const float*)d_in[15];
    const float* g_se_b = (const float*)d_in[16];
    const float* g_oe_w = (const float*)d_in[17];
    const float* g_oe_b = (const float*)d_in[18];
    const float* ngru_wih = (const float*)d_in[19];
    const float* ngru_whh = (const float*)d_in[20];
    const float* ngru_bih = (const float*)d_in[21];
    const float* ngru_bhh = (const float*)d_in[22];
    const float* egru_wih = (const float*)d_in[23];
    const float* egru_whh = (const float*)d_in[24];
    const float* egru_bih = (const float*)d_in[25];
    const float* egru_bhh = (const float*)d_in[26];
    const float* op_w = (const float*)d_in[27];
    const float* op_b = (const float*)d_in[28];
    const float* pp_w = (const float*)d_in[29];
    const float* pp_b = (const float*)d_in[30];

    float* out = (float*)d_out;
    float* ws = (float*)d_ws;

    float* h_obj = out + OFF_HOBJ;       // in-place GRU state in d_out
    float* h_edge = out + OFF_HEDGE;

    // workspace layout
    float* tmp_e = ws;                                  // 32768*512 (enc hidden / em)
    float* tmp_o = tmp_e + (size_t)N_RELS * DIM;        // 2048*512 (enc hidden / nm)
    float* cnts = tmp_o + (size_t)N_OBJS * DIM;         // 2*N_OBJS
    float* cnt_s = cnts;
    float* cnt_o = cnts + N_OBJS;
    float* em = tmp_e;
    float* nm = tmp_o;

    // f16 weight area (hi only); classifier allocs padded to 128-row multiples
    u16* wp = (u16*)(cnts + 2 * N_OBJS);
    const int s_big = DIM * D_IN, s_sq = DIM * DIM, s_gru = 3 * DIM * DIM;
    const int s_op_pad = 256 * DIM, s_pp_pad = 128 * DIM;
    u16 *oe1h = wp; wp += s_big;
    u16 *pe1h = wp; wp += s_big;
    u16 *oe2h = wp; wp += s_sq;
    u16 *pe2h = wp; wp += s_sq;
    u16 *nih_h = wp; wp += s_gru;
    u16 *nhh_h = wp; wp += s_gru;
    u16 *eih_h = wp; wp += s_gru;
    u16 *ehh_h = wp; wp += s_gru;
    u16 *oph = wp; wp += s_op_pad;
    u16 *pph = wp; wp += s_pp_pad;

    // GRU chunk buffers: act splits 4 x R*512 u16 + gi/gh 2 x R*1536 u16
    // => 10240 bytes per row
    const size_t used = (size_t)((char*)wp - (char*)ws);
    int R = 2048;
    if (used + (size_t)8192 * 10240 <= ws_size) R = 8192;
    else if (used + (size_t)4096 * 10240 <= ws_size) R = 4096;
    u16* cxh = wp;
    u16* cxl = cxh + (size_t)R * DIM;
    u16* chh = cxl + (size_t)R * DIM;
    u16* chl = chh + (size_t)R * DIM;
    u16* gi = chl + (size_t)R * DIM;
    u16* gh = gi + (size_t)R * 1536;

    auto cvtw = [&](const float* s, u16* h, int n) {
        convert_h<<<(n / 4 + 255) / 256, 256, 0, stream>>>(s, h, n / 4);
    };
    cvtw(oe_w1, oe1h, s_big);
    cvtw(pe_w1, pe1h, s_big);
    cvtw(oe_w2, oe2h, s_sq);
    cvtw(pe_w2, pe2h, s_sq);
    cvtw(ngru_wih, nih_h, s_gru);
    cvtw(ngru_whh, nhh_h, s_gru);
    cvtw(egru_wih, eih_h, s_gru);
    cvtw(egru_whh, ehh_h, s_gru);
    cvtw(op_w, oph, N_OBJ_CLS * DIM);
    cvtw(pp_w, pph, N_REL_CLS * DIM);

    // degree counts
    hipMemsetAsync(cnts, 0, 2 * N_OBJS * sizeof(float), stream);
    count_kernel<<<N_RELS / 256, 256, 0, stream>>>(rel, cnt_s, cnt_o);

    // encoders (enc2 writes h directly into d_out; GRU updates in place)
    gemm_split<true><<<dim3(DIM / 128, N_OBJS / 128), 256, 0, stream>>>(
        x_obj, oe1h, oe_b1, tmp_o, N_OBJS, DIM, D_IN);
    gemm_split<false><<<dim3(DIM / 128, N_OBJS / 128), 256, 0, stream>>>(
        tmp_o, oe2h, oe_b2, h_obj, N_OBJS, DIM, DIM);
    gemm_split<true><<<dim3(DIM / 128, N_RELS / 128), 256, 0, stream>>>(
        x_pred, pe1h, pe_b1, tmp_e, N_RELS, DIM, D_IN);
    gemm_split<false><<<dim3(DIM / 128, N_RELS / 128), 256, 0, stream>>>(
        tmp_e, pe2h, pe_b2, h_edge, N_RELS, DIM, DIM);

    // chunked two-pass GRU, in-place on H
    auto run_gru = [&](const float* X, float* H,
                       const u16* WiH, const u16* WhH,
                       const float* bih, const float* bhh, int Mtot) {
        for (int r0 = 0; r0 < Mtot; r0 += R) {
            const int Rc = (Mtot - r0 < R) ? (Mtot - r0) : R;
            convert_hl<<<(Rc * 128 + 255) / 256, 256, 0, stream>>>(
                X + (size_t)r0 * DIM, cxh, cxl, Rc * 128);
            convert_hl<<<(Rc * 128 + 255) / 256, 256, 0, stream>>>(
                H + (size_t)r0 * DIM, chh, chl, Rc * 128);
            gru_gemm2<<<dim3(24, Rc / 128), 256, 0, stream>>>(
                cxh, cxl, WiH, bih, gi, chh, chl, WhH, bhh, gh, DIM);
            gru_combine<<<(Rc * 128 + 255) / 256, 256, 0, stream>>>(
                gi, gh, H + (size_t)r0 * DIM, H + (size_t)r0 * DIM, Rc);
        }
    };

    // message-passing steps (in-place state in d_out)
    for (int step = 0; step < 2; step++) {
        hipMemsetAsync(nm, 0, (size_t)N_OBJS * DIM * sizeof(float), stream);
        gatepass<<<N_RELS, 256, 0, stream>>>(
            h_obj, h_edge, rel,
            g_sn_w, g_sn_b, g_on_w, g_on_b, g_se_w, g_se_b, g_oe_w, g_oe_b,
            cnt_s, cnt_o, nm, em);
        run_gru(nm, h_obj, nih_h, nhh_h, ngru_bih, ngru_bhh, N_OBJS);
        run_gru(em, h_edge, eih_h, ehh_h, egru_bih, egru_bhh, N_RELS);
    }

    // classifiers (fp32 A from d_out, padded f16 weights)
    gemm_split<false><<<dim3((N_OBJ_CLS + 127) / 128, N_OBJS / 128), 256, 0, stream>>>(
        h_obj, oph, op_b, out + OFF_OLOG, N_OBJS, N_OBJ_CLS, DIM);
    gemm_split<false><<<dim3((N_REL_CLS + 127) / 128, N_RELS / 128), 256, 0, stream>>>(
        h_edge, pph, pp_b, out + OFF_PLOG, N_RELS, N_REL_CLS, DIM);

    // labels + rel_inds passthrough
    argmax_kernel<<<N_OBJS / 4, 256, 0, stream>>>(out + OFF_OLOG, out + OFF_LBL);
    relinds_kernel<<<(2 * N_RELS) / 256, 256, 0, stream>>>(rel, out + OFF_RI);
}

// Round 6
// 1769.398 us; speedup vs baseline: 1.4129x; 1.1021x over previous
//
#include <hip/hip_runtime.h>
#include <math.h>

typedef unsigned short u16;
typedef unsigned int u32;
typedef _Float16 f16;
typedef f16 f16x8 __attribute__((ext_vector_type(8)));
typedef float f32x4 __attribute__((ext_vector_type(4)));

#define DIM 512
#define D_IN 4096
#define N_OBJS 2048
#define N_RELS 32768
#define N_OBJ_CLS 151
#define N_REL_CLS 51
#define EPSV 1e-5f

// d_out layout (floats)
#define OFF_HOBJ  0
#define OFF_HEDGE (N_OBJS*DIM)
#define OFF_OLOG  (OFF_HEDGE + N_RELS*DIM)
#define OFF_PLOG  (OFF_OLOG + N_OBJS*N_OBJ_CLS)
#define OFF_LBL   (OFF_PLOG + N_RELS*N_REL_CLS)
#define OFF_RI    (OFF_LBL + N_OBJS)

__device__ __forceinline__ float sigmoidf_(float x) { return 1.0f / (1.0f + expf(-x)); }
__device__ __forceinline__ u16 f2h_(float f) {
    union { f16 h; u16 u; } c; c.h = (f16)f; return c.u;
}
__device__ __forceinline__ float h2f_(u16 u) {
    union { f16 h; u16 u; } c; c.u = u; return (float)c.h;
}

// 8 fp32 -> packed f16 hi (uint4) + f16 lo (uint4); a ~= hi + lo to 2^-24
__device__ __forceinline__ void cvt8h(const float* f, uint4& h, uint4& l) {
    u32 hh[8], ll[8];
#pragma unroll
    for (int i = 0; i < 8; i++) {
        u16 x = f2h_(f[i]);
        hh[i] = x;
        ll[i] = f2h_(f[i] - h2f_(x));
    }
    h.x = hh[0] | (hh[1] << 16); h.y = hh[2] | (hh[3] << 16);
    h.z = hh[4] | (hh[5] << 16); h.w = hh[6] | (hh[7] << 16);
    l.x = ll[0] | (ll[1] << 16); l.y = ll[2] | (ll[3] << 16);
    l.z = ll[4] | (ll[5] << 16); l.w = ll[6] | (ll[7] << 16);
}

// LDS offset (u16 units) for (row, chunk8) in a [rows][32] tile, XOR-swizzled
__device__ __forceinline__ int swzo(int row, int c) {
    return row * 32 + ((c ^ ((row >> 1) & 3)) << 3);
}

// XCD-chunked bijective blockIdx swizzle (requires nwg % 8 == 0): blocks that
// round-robin onto XCD x process a CONTIGUOUS chunk of logical ids -> co-XCD
// blocks share A panels in that XCD's L2.
__device__ __forceinline__ int xcdswz(int orig, int nwg) {
    const int q = nwg >> 3;
    return (orig & 7) * q + (orig >> 3);
}

// async global->LDS, 16B per lane; LDS dest = wave-uniform base + lane*16
__device__ __forceinline__ void gload16(const void* g, void* l) {
    __builtin_amdgcn_global_load_lds(
        (const __attribute__((address_space(1))) void*)g,
        (__attribute__((address_space(3))) void*)l, 16, 0, 0);
}

// ---------------------------------------------------------------------------
// weights: fp32 -> f16 hi only
__global__ __launch_bounds__(256) void convert_h(const float* __restrict__ src,
    u16* __restrict__ hi, int n4)
{
    const int i = blockIdx.x * 256 + threadIdx.x;
    if (i >= n4) return;
    const float4 v = ((const float4*)src)[i];
    ((ushort4*)hi)[i] = make_ushort4(f2h_(v.x), f2h_(v.y), f2h_(v.z), f2h_(v.w));
}

// activations: fp32 -> f16 hi + lo
__global__ __launch_bounds__(256) void convert_hl(const float* __restrict__ src,
    u16* __restrict__ hi, u16* __restrict__ lo, int n4)
{
    const int i = blockIdx.x * 256 + threadIdx.x;
    if (i >= n4) return;
    const float4 v = ((const float4*)src)[i];
    u16 h0 = f2h_(v.x), h1 = f2h_(v.y), h2 = f2h_(v.z), h3 = f2h_(v.w);
    ((ushort4*)hi)[i] = make_ushort4(h0, h1, h2, h3);
    ((ushort4*)lo)[i] = make_ushort4(f2h_(v.x - h2f_(h0)), f2h_(v.y - h2f_(h1)),
                                     f2h_(v.z - h2f_(h2)), f2h_(v.w - h2f_(h3)));
}

// ---------------------------------------------------------------------------
// 2-term f16 GEMM, fp32 A split on the fly, B f16-hi via global_load_lds.
// SPLITOUT: write act(C) as f16 hi/lo (for downstream presplit GEMMs);
// else write f32 C. 1D grid, XCD-swizzled; NX = n-blocks (fastest dim).
// ---------------------------------------------------------------------------
template<bool RELU, bool SPLITOUT>
__global__ __launch_bounds__(256, 2) void gemm_split(
    const float* __restrict__ A, const u16* __restrict__ Bhi,
    const float* __restrict__ bias, float* __restrict__ C,
    u16* __restrict__ Chi, u16* __restrict__ Clo, int NX, int N, int K)
{
    __shared__ u16 sAh[128 * 32], sAl[128 * 32], sBh[128 * 32];
    const int id = xcdswz(blockIdx.x, gridDim.x);
    const int m0 = (id / NX) * 128, n0 = (id % NX) * 128;
    const int t = threadIdx.x;
    const int wid = t >> 6, lane = t & 63;
    const int wm = (wid >> 1) * 64, wn = (wid & 1) * 64;
    const int lr = lane & 15, lk = lane >> 4;

    f32x4 acc[4][4] = {};

    const int sr = t >> 1;
    const int sc = (t & 1) * 2;
    const float* Ap = A + (size_t)(m0 + sr) * K + (t & 1) * 16;

    // per-lane pre-swizzled global source for B staging (linear LDS dest)
    const int rB = (wid * 2) * 16 + (lane >> 2);
    const int cB = (lane & 3) ^ ((rB >> 1) & 3);
    const u16* Bp0 = Bhi + (size_t)(n0 + rB) * K + cB * 8;
    const u16* Bp1 = Bp0 + (size_t)16 * K;
    u16* Bd0 = &sBh[(wid * 2) * 512];
    u16* Bd1 = Bd0 + 512;

    for (int k0 = 0; k0 < K; k0 += 32) {
        float fv[16];
        *(float4*)&fv[0]  = *(const float4*)(Ap + k0);
        *(float4*)&fv[4]  = *(const float4*)(Ap + k0 + 4);
        *(float4*)&fv[8]  = *(const float4*)(Ap + k0 + 8);
        *(float4*)&fv[12] = *(const float4*)(Ap + k0 + 12);
        uint4 ah0, ah1, al0, al1;
        cvt8h(fv, ah0, al0); cvt8h(fv + 8, ah1, al1);

        __syncthreads();                       // previous reads complete
        gload16(Bp0 + k0, Bd0);
        gload16(Bp1 + k0, Bd1);
        *(uint4*)&sAh[swzo(sr, sc)]     = ah0;
        *(uint4*)&sAh[swzo(sr, sc + 1)] = ah1;
        *(uint4*)&sAl[swzo(sr, sc)]     = al0;
        *(uint4*)&sAl[swzo(sr, sc + 1)] = al1;
        asm volatile("s_waitcnt vmcnt(0)" ::: "memory");
        __syncthreads();

        f16x8 ah[4], al[4], bh[4];
#pragma unroll
        for (int f = 0; f < 4; f++) {
            const int off = swzo(wm + f * 16 + lr, lk);
            ah[f] = *(const f16x8*)&sAh[off];
            al[f] = *(const f16x8*)&sAl[off];
            bh[f] = *(const f16x8*)&sBh[swzo(wn + f * 16 + lr, lk)];
        }
#pragma unroll
        for (int fm = 0; fm < 4; fm++)
#pragma unroll
            for (int fn = 0; fn < 4; fn++) {
                acc[fm][fn] = __builtin_amdgcn_mfma_f32_16x16x32_f16(ah[fm], bh[fn], acc[fm][fn], 0, 0, 0);
                acc[fm][fn] = __builtin_amdgcn_mfma_f32_16x16x32_f16(al[fm], bh[fn], acc[fm][fn], 0, 0, 0);
            }
    }
#pragma unroll
    for (int fm = 0; fm < 4; fm++) {
        const int mrow = m0 + wm + fm * 16 + lk * 4;
#pragma unroll
        for (int fn = 0; fn < 4; fn++) {
            const int col = n0 + wn + fn * 16 + lr;
            if (col < N) {
                const float bv = bias[col];
#pragma unroll
                for (int j = 0; j < 4; j++) {
                    float v = acc[fm][fn][j] + bv;
                    if (RELU) v = fmaxf(v, 0.0f);
                    if (SPLITOUT) {
                        const u16 h = f2h_(v);
                        Chi[(size_t)(mrow + j) * N + col] = h;
                        Clo[(size_t)(mrow + j) * N + col] = f2h_(v - h2f_(h));
                    } else {
                        C[(size_t)(mrow + j) * N + col] = v;
                    }
                }
            }
        }
    }
}

// ---------------------------------------------------------------------------
// All-presplit 2-term f16 GEMM (A hi/lo, B hi via global_load_lds), f32 out.
// N = NX*128 exact (no bounds checks). 1D grid, XCD-swizzled.
// ---------------------------------------------------------------------------
__global__ __launch_bounds__(256, 3) void gemm_ps(
    const u16* __restrict__ Ahi, const u16* __restrict__ Alo,
    const u16* __restrict__ Bhi, const float* __restrict__ bias,
    float* __restrict__ C, int NX, int K)
{
    __shared__ u16 sAh[128 * 32], sAl[128 * 32], sBh[128 * 32];
    const int id = xcdswz(blockIdx.x, gridDim.x);
    const int m0 = (id / NX) * 128, n0 = (id % NX) * 128;
    const int N = NX * 128;
    const int t = threadIdx.x;
    const int wid = t >> 6, lane = t & 63;
    const int wm = (wid >> 1) * 64, wn = (wid & 1) * 64;
    const int lr = lane & 15, lk = lane >> 4;

    f32x4 acc[4][4] = {};

    const int rr = (wid * 2) * 16 + (lane >> 2);
    const int cc = (lane & 3) ^ ((rr >> 1) & 3);
    const size_t aoff = (size_t)(m0 + rr) * K + cc * 8;
    const size_t boff = (size_t)(n0 + rr) * K + cc * 8;
    const u16* pAh0 = Ahi + aoff; const u16* pAh1 = pAh0 + (size_t)16 * K;
    const u16* pAl0 = Alo + aoff; const u16* pAl1 = pAl0 + (size_t)16 * K;
    const u16* pB0 = Bhi + boff;  const u16* pB1 = pB0 + (size_t)16 * K;
    u16* dAh0 = &sAh[(wid * 2) * 512]; u16* dAh1 = dAh0 + 512;
    u16* dAl0 = &sAl[(wid * 2) * 512]; u16* dAl1 = dAl0 + 512;
    u16* dB0  = &sBh[(wid * 2) * 512]; u16* dB1  = dB0 + 512;

    for (int k0 = 0; k0 < K; k0 += 32) {
        __syncthreads();
        gload16(pAh0 + k0, dAh0); gload16(pAh1 + k0, dAh1);
        gload16(pAl0 + k0, dAl0); gload16(pAl1 + k0, dAl1);
        gload16(pB0 + k0, dB0);   gload16(pB1 + k0, dB1);
        asm volatile("s_waitcnt vmcnt(0)" ::: "memory");
        __syncthreads();

        f16x8 ah[4], al[4], bh[4];
#pragma unroll
        for (int f = 0; f < 4; f++) {
            const int off = swzo(wm + f * 16 + lr, lk);
            ah[f] = *(const f16x8*)&sAh[off];
            al[f] = *(const f16x8*)&sAl[off];
            bh[f] = *(const f16x8*)&sBh[swzo(wn + f * 16 + lr, lk)];
        }
#pragma unroll
        for (int fm = 0; fm < 4; fm++)
#pragma unroll
            for (int fn = 0; fn < 4; fn++) {
                acc[fm][fn] = __builtin_amdgcn_mfma_f32_16x16x32_f16(ah[fm], bh[fn], acc[fm][fn], 0, 0, 0);
                acc[fm][fn] = __builtin_amdgcn_mfma_f32_16x16x32_f16(al[fm], bh[fn], acc[fm][fn], 0, 0, 0);
            }
    }
#pragma unroll
    for (int fm = 0; fm < 4; fm++) {
        const int mrow = m0 + wm + fm * 16 + lk * 4;
#pragma unroll
        for (int fn = 0; fn < 4; fn++) {
            const int col = n0 + wn + fn * 16 + lr;
            const float bv = bias[col];
#pragma unroll
            for (int j = 0; j < 4; j++)
                C[(size_t)(mrow + j) * N + col] = acc[fm][fn][j] + bv;
        }
    }
}

// ---------------------------------------------------------------------------
// Merged GRU GEMM (2-term f16, all presplit, gload_lds): logical block part<12
// -> gi = X@Wih^T+bih; part>=12 -> gh = H@Whh^T+bhh. f16 out, ldc=1536.
// 1D grid (24 * M/128), XCD-swizzled.
// ---------------------------------------------------------------------------
__global__ __launch_bounds__(256, 3) void gru_gemm2(
    const u16* __restrict__ Xh, const u16* __restrict__ Xl,
    const u16* __restrict__ WiH, const float* __restrict__ bi, u16* __restrict__ gi,
    const u16* __restrict__ Hh, const u16* __restrict__ Hl,
    const u16* __restrict__ WhH, const float* __restrict__ bhs, u16* __restrict__ gh_,
    int K)
{
    __shared__ u16 sAh[128 * 32], sAl[128 * 32], sBh[128 * 32];
    const int id = xcdswz(blockIdx.x, gridDim.x);
    const int part = id % 24;
    const int m0 = (id / 24) * 128;
    const bool isH = part >= 12;
    const u16* Ahi = isH ? Hh : Xh;
    const u16* Alo = isH ? Hl : Xl;
    const u16* Bhi = isH ? WhH : WiH;
    const float* bias = isH ? bhs : bi;
    u16* C = isH ? gh_ : gi;
    const int n0 = (part - (isH ? 12 : 0)) * 128;

    const int t = threadIdx.x;
    const int wid = t >> 6, lane = t & 63;
    const int wm = (wid >> 1) * 64, wn = (wid & 1) * 64;
    const int lr = lane & 15, lk = lane >> 4;

    f32x4 acc[4][4] = {};

    const int rr = (wid * 2) * 16 + (lane >> 2);
    const int cc = (lane & 3) ^ ((rr >> 1) & 3);
    const size_t aoff = (size_t)(m0 + rr) * K + cc * 8;
    const size_t boff = (size_t)(n0 + rr) * K + cc * 8;
    const u16* pAh0 = Ahi + aoff; const u16* pAh1 = pAh0 + (size_t)16 * K;
    const u16* pAl0 = Alo + aoff; const u16* pAl1 = pAl0 + (size_t)16 * K;
    const u16* pB0 = Bhi + boff;  const u16* pB1 = pB0 + (size_t)16 * K;
    u16* dAh0 = &sAh[(wid * 2) * 512]; u16* dAh1 = dAh0 + 512;
    u16* dAl0 = &sAl[(wid * 2) * 512]; u16* dAl1 = dAl0 + 512;
    u16* dB0  = &sBh[(wid * 2) * 512]; u16* dB1  = dB0 + 512;

    for (int k0 = 0; k0 < K; k0 += 32) {
        __syncthreads();
        gload16(pAh0 + k0, dAh0); gload16(pAh1 + k0, dAh1);
        gload16(pAl0 + k0, dAl0); gload16(pAl1 + k0, dAl1);
        gload16(pB0 + k0, dB0);   gload16(pB1 + k0, dB1);
        asm volatile("s_waitcnt vmcnt(0)" ::: "memory");
        __syncthreads();

        f16x8 ah[4], al[4], bh[4];
#pragma unroll
        for (int f = 0; f < 4; f++) {
            const int off = swzo(wm + f * 16 + lr, lk);
            ah[f] = *(const f16x8*)&sAh[off];
            al[f] = *(const f16x8*)&sAl[off];
            bh[f] = *(const f16x8*)&sBh[swzo(wn + f * 16 + lr, lk)];
        }
#pragma unroll
        for (int fm = 0; fm < 4; fm++)
#pragma unroll
            for (int fn = 0; fn < 4; fn++) {
                acc[fm][fn] = __builtin_amdgcn_mfma_f32_16x16x32_f16(ah[fm], bh[fn], acc[fm][fn], 0, 0, 0);
                acc[fm][fn] = __builtin_amdgcn_mfma_f32_16x16x32_f16(al[fm], bh[fn], acc[fm][fn], 0, 0, 0);
            }
    }
#pragma unroll
    for (int fm = 0; fm < 4; fm++) {
        const int mrow = m0 + wm + fm * 16 + lk * 4;
#pragma unroll
        for (int fn = 0; fn < 4; fn++) {
            const int col = n0 + wn + fn * 16 + lr;
            const float bv = bias[col];
#pragma unroll
            for (int j = 0; j < 4; j++)
                C[(size_t)(mrow + j) * 1536 + col] = f2h_(acc[fm][fn][j] + bv);
        }
    }
}

// ---------------------------------------------------------------------------
// GRU pointwise combine: gi/gh f16 [R x 1536] (r,z,n), H/Hout f32 [R x 512]
// ---------------------------------------------------------------------------
__device__ __forceinline__ float gcomb(u16 ir, u16 iz, u16 in_, u16 hr, u16 hz,
                                       u16 hn, float h) {
    const float r = sigmoidf_(h2f_(ir) + h2f_(hr));
    const float z = sigmoidf_(h2f_(iz) + h2f_(hz));
    const float n = tanhf(h2f_(in_) + r * h2f_(hn));
    return (1.0f - z) * n + z * h;
}

__global__ __launch_bounds__(256) void gru_combine(
    const u16* __restrict__ gi, const u16* __restrict__ gh,
    const float* __restrict__ H, float* __restrict__ Hout, int R)
{
    const int idx = blockIdx.x * 256 + threadIdx.x;      // R*128 quads
    if (idx >= R * 128) return;
    const int r = idx >> 7, c4 = (idx & 127) * 4;
    const size_t gb = (size_t)r * 1536 + c4;
    const ushort4 ir4 = *(const ushort4*)&gi[gb];
    const ushort4 iz4 = *(const ushort4*)&gi[gb + 512];
    const ushort4 in4 = *(const ushort4*)&gi[gb + 1024];
    const ushort4 hr4 = *(const ushort4*)&gh[gb];
    const ushort4 hz4 = *(const ushort4*)&gh[gb + 512];
    const ushort4 hn4 = *(const ushort4*)&gh[gb + 1024];
    const float4 h4 = *(const float4*)&H[(size_t)r * 512 + c4];
    float4 o;
    o.x = gcomb(ir4.x, iz4.x, in4.x, hr4.x, hz4.x, hn4.x, h4.x);
    o.y = gcomb(ir4.y, iz4.y, in4.y, hr4.y, hz4.y, hn4.y, h4.y);
    o.z = gcomb(ir4.z, iz4.z, in4.z, hr4.z, hz4.z, hn4.z, h4.z);
    o.w = gcomb(ir4.w, iz4.w, in4.w, hr4.w, hz4.w, hn4.w, h4.w);
    *(float4*)&Hout[(size_t)r * 512 + c4] = o;
}

// ---------------------------------------------------------------------------
__global__ __launch_bounds__(256) void count_kernel(const int* __restrict__ rel,
                                                    float* cnt_s, float* cnt_o)
{
    const int e = blockIdx.x * 256 + threadIdx.x;
    atomicAdd(&cnt_s[rel[2 * e]], 1.0f);
    atomicAdd(&cnt_o[rel[2 * e + 1]], 1.0f);
}

// ---------------------------------------------------------------------------
// Fused gates + message pass: one block (256 thr) per edge. Writes em
// DIRECTLY as f16 hi/lo (consumed by presplit GRU GEMM); nm stays f32 atomics.
// ---------------------------------------------------------------------------
__global__ __launch_bounds__(256) void gatepass(
    const float* __restrict__ h_obj, const float* __restrict__ h_edge,
    const int* __restrict__ rel,
    const float* __restrict__ wsn, const float* __restrict__ bsn,
    const float* __restrict__ won, const float* __restrict__ bon,
    const float* __restrict__ wse, const float* __restrict__ bse,
    const float* __restrict__ woe, const float* __restrict__ boe,
    const float* __restrict__ cnt_s, const float* __restrict__ cnt_o,
    float* __restrict__ nm, u16* __restrict__ emh, u16* __restrict__ eml)
{
    __shared__ float red[4][4];
    const int e = blockIdx.x;
    const int t = threadIdx.x;
    const int wid = t >> 6, lane = t & 63;
    const int s = rel[2 * e], o = rel[2 * e + 1];
    const int c = 2 * t;

    const float2 hs = *(const float2*)&h_obj[(size_t)s * DIM + c];
    const float2 ho = *(const float2*)&h_obj[(size_t)o * DIM + c];
    const float2 he = *(const float2*)&h_edge[(size_t)e * DIM + c];

    const float2 w0v = *(const float2*)&wsn[c], w0e = *(const float2*)&wsn[DIM + c];
    const float2 w1v = *(const float2*)&won[c], w1e = *(const float2*)&won[DIM + c];
    const float2 w2v = *(const float2*)&wse[c], w2e = *(const float2*)&wse[DIM + c];
    const float2 w3v = *(const float2*)&woe[c], w3e = *(const float2*)&woe[DIM + c];

    float p0 = hs.x * w0v.x + hs.y * w0v.y + he.x * w0e.x + he.y * w0e.y;
    float p1 = ho.x * w1v.x + ho.y * w1v.y + he.x * w1e.x + he.y * w1e.y;
    float p2 = hs.x * w2v.x + hs.y * w2v.y + he.x * w2e.x + he.y * w2e.y;
    float p3 = ho.x * w3v.x + ho.y * w3v.y + he.x * w3e.x + he.y * w3e.y;

#pragma unroll
    for (int off = 32; off; off >>= 1) {
        p0 += __shfl_xor(p0, off);
        p1 += __shfl_xor(p1, off);
        p2 += __shfl_xor(p2, off);
        p3 += __shfl_xor(p3, off);
    }
    if (lane == 0) { red[wid][0] = p0; red[wid][1] = p1; red[wid][2] = p2; red[wid][3] = p3; }
    __syncthreads();
    const float gsn = sigmoidf_(red[0][0] + red[1][0] + red[2][0] + red[3][0] + bsn[0]);
    const float gon = sigmoidf_(red[0][1] + red[1][1] + red[2][1] + red[3][1] + bon[0]);
    const float gse = sigmoidf_(red[0][2] + red[1][2] + red[2][2] + red[3][2] + bse[0]);
    const float goe = sigmoidf_(red[0][3] + red[1][3] + red[2][3] + red[3][3] + boe[0]);

    const float as = 0.5f * gsn / (cnt_s[s] + EPSV);
    const float ao = 0.5f * gon / (cnt_o[o] + EPSV);

    atomicAdd(&nm[(size_t)s * DIM + c],     as * he.x);
    atomicAdd(&nm[(size_t)s * DIM + c + 1], as * he.y);
    atomicAdd(&nm[(size_t)o * DIM + c],     ao * he.x);
    atomicAdd(&nm[(size_t)o * DIM + c + 1], ao * he.y);

    const float ex = 0.5f * (gse * hs.x + goe * ho.x);
    const float ey = 0.5f * (gse * hs.y + goe * ho.y);
    const u16 hx = f2h_(ex), hy = f2h_(ey);
    *(u32*)&emh[(size_t)e * DIM + c] = (u32)hx | ((u32)hy << 16);
    *(u32*)&eml[(size_t)e * DIM + c] =
        (u32)f2h_(ex - h2f_(hx)) | ((u32)f2h_(ey - h2f_(hy)) << 16);
}

__global__ __launch_bounds__(256) void argmax_kernel(const float* __restrict__ logits,
                                                     float* __restrict__ out)
{
    const int row = blockIdx.x * 4 + (threadIdx.x >> 6);
    const int lane = threadIdx.x & 63;
    float bv = -1e30f; int bi = 1;
    for (int j = 1 + lane; j < N_OBJ_CLS; j += 64) {
        const float v = logits[(size_t)row * N_OBJ_CLS + j];
        if (v > bv) { bv = v; bi = j; }
    }
#pragma unroll
    for (int off = 32; off; off >>= 1) {
        const float ov = __shfl_xor(bv, off);
        const int oi = __shfl_xor(bi, off);
        if (ov > bv || (ov == bv && oi < bi)) { bv = ov; bi = oi; }
    }
    if (lane == 0) out[row] = (float)bi;
}

__global__ __launch_bounds__(256) void relinds_kernel(const int* __restrict__ rel,
                                                      float* __restrict__ out)
{
    const int i = blockIdx.x * 256 + threadIdx.x;
    out[i] = (float)rel[i];
}

// ---------------------------------------------------------------------------
extern "C" void kernel_launch(void* const* d_in, const int* in_sizes, int n_in,
                              void* d_out, int out_size, void* d_ws, size_t ws_size,
                              hipStream_t stream)
{
    const float* x_obj = (const float*)d_in[0];
    const float* x_pred = (const float*)d_in[1];
    const int* rel = (const int*)d_in[2];
    const float* oe_w1 = (const float*)d_in[3];
    const float* oe_b1 = (const float*)d_in[4];
    const float* oe_w2 = (const float*)d_in[5];
    const float* oe_b2 = (const float*)d_in[6];
    const float* pe_w1 = (const float*)d_in[7];
    const float* pe_b1 = (const float*)d_in[8];
    const float* pe_w2 = (const float*)d_in[9];
    const float* pe_b2 = (const float*)d_in[10];
    const float* g_sn_w = (const float*)d_in[11];
    const float* g_sn_b = (const float*)d_in[12];
    const float* g_on_w = (const float*)d_in[13];
    const float* g_on_b = (const float*)d_in[14];
    const float* g_se_w = (const float*)d_in[15];
    const float* g_se_b = (const float*)d_in[16];
    const float* g_oe_w = (const float*)d_in[17];
    const float* g_oe_b = (const float*)d_in[18];
    const float* ngru_wih = (const float*)d_in[19];
    const float* ngru_whh = (const float*)d_in[20];
    const float* ngru_bih = (const float*)d_in[21];
    const float* ngru_bhh = (const float*)d_in[22];
    const float* egru_wih = (const float*)d_in[23];
    const float* egru_whh = (const float*)d_in[24];
    const float* egru_bih = (const float*)d_in[25];
    const float* egru_bhh = (const float*)d_in[26];
    const float* op_w = (const float*)d_in[27];
    const float* op_b = (const float*)d_in[28];
    const float* pp_w = (const float*)d_in[29];
    const float* pp_b = (const float*)d_in[30];

    float* out = (float*)d_out;
    float* ws = (float*)d_ws;

    float* h_obj = out + OFF_HOBJ;       // in-place GRU state in d_out
    float* h_edge = out + OFF_HEDGE;

    // f32 workspace
    float* nm = ws;                                     // 2048*512
    float* cnts = nm + (size_t)N_OBJS * DIM;            // 2*N_OBJS
    float* cnt_s = cnts;
    float* cnt_o = cnts + N_OBJS;

    // u16 area
    u16* wp = (u16*)(cnts + 2 * N_OBJS);
    const int s_big = DIM * D_IN, s_sq = DIM * DIM, s_gru = 3 * DIM * DIM;
    const int s_op_pad = 256 * DIM, s_pp_pad = 128 * DIM;
    // weights (f16 hi)
    u16 *oe1h = wp; wp += s_big;
    u16 *pe1h = wp; wp += s_big;
    u16 *oe2h = wp; wp += s_sq;
    u16 *pe2h = wp; wp += s_sq;
    u16 *nih_h = wp; wp += s_gru;
    u16 *nhh_h = wp; wp += s_gru;
    u16 *eih_h = wp; wp += s_gru;
    u16 *ehh_h = wp; wp += s_gru;
    u16 *oph = wp; wp += s_op_pad;
    u16 *pph = wp; wp += s_pp_pad;
    // activation splits
    u16 *tmpe_h = wp; wp += (size_t)N_RELS * DIM;       // enc1-edge out
    u16 *tmpe_l = wp; wp += (size_t)N_RELS * DIM;
    u16 *tmpo_h = wp; wp += (size_t)N_OBJS * DIM;       // enc1-obj out
    u16 *tmpo_l = wp; wp += (size_t)N_OBJS * DIM;
    u16 *emh = wp; wp += (size_t)N_RELS * DIM;          // edge messages (split)
    u16 *eml = wp; wp += (size_t)N_RELS * DIM;
    u16 *nmh = wp; wp += (size_t)N_OBJS * DIM;          // node messages (split)
    u16 *nml = wp; wp += (size_t)N_OBJS * DIM;

    // chunk buffers: H split (2 x R*512 u16) + gi/gh (2 x R*1536 u16)
    // => 8192 bytes per row
    const size_t used = (size_t)((char*)wp - (char*)ws);
    int R = 2048;
    if (used + (size_t)8192 * 8192 <= ws_size) R = 8192;
    else if (used + (size_t)4096 * 8192 <= ws_size) R = 4096;
    u16* chh = wp;
    u16* chl = chh + (size_t)R * DIM;
    u16* gi = chl + (size_t)R * DIM;
    u16* gh = gi + (size_t)R * 1536;

    auto cvtw = [&](const float* s, u16* h, int n) {
        convert_h<<<(n / 4 + 255) / 256, 256, 0, stream>>>(s, h, n / 4);
    };
    cvtw(oe_w1, oe1h, s_big);
    cvtw(pe_w1, pe1h, s_big);
    cvtw(oe_w2, oe2h, s_sq);
    cvtw(pe_w2, pe2h, s_sq);
    cvtw(ngru_wih, nih_h, s_gru);
    cvtw(ngru_whh, nhh_h, s_gru);
    cvtw(egru_wih, eih_h, s_gru);
    cvtw(egru_whh, ehh_h, s_gru);
    cvtw(op_w, oph, N_OBJ_CLS * DIM);
    cvtw(pp_w, pph, N_REL_CLS * DIM);

    // degree counts
    hipMemsetAsync(cnts, 0, 2 * N_OBJS * sizeof(float), stream);
    count_kernel<<<N_RELS / 256, 256, 0, stream>>>(rel, cnt_s, cnt_o);

    // encoders: enc1 emits split directly; enc2 is all-presplit, writes f32 h
    gemm_split<true, true><<<4 * (N_OBJS / 128), 256, 0, stream>>>(
        x_obj, oe1h, oe_b1, nullptr, tmpo_h, tmpo_l, 4, DIM, D_IN);
    gemm_ps<<<4 * (N_OBJS / 128), 256, 0, stream>>>(
        tmpo_h, tmpo_l, oe2h, oe_b2, h_obj, 4, DIM);
    gemm_split<true, true><<<4 * (N_RELS / 128), 256, 0, stream>>>(
        x_pred, pe1h, pe_b1, nullptr, tmpe_h, tmpe_l, 4, DIM, D_IN);
    gemm_ps<<<4 * (N_RELS / 128), 256, 0, stream>>>(
        tmpe_h, tmpe_l, pe2h, pe_b2, h_edge, 4, DIM);

    // chunked two-pass GRU, in-place on H; X already split (Xh/Xl full arrays)
    auto run_gru = [&](const u16* Xh, const u16* Xl, float* H,
                       const u16* WiH, const u16* WhH,
                       const float* bih, const float* bhh, int Mtot) {
        for (int r0 = 0; r0 < Mtot; r0 += R) {
            const int Rc = (Mtot - r0 < R) ? (Mtot - r0) : R;
            convert_hl<<<(Rc * 128 + 255) / 256, 256, 0, stream>>>(
                H + (size_t)r0 * DIM, chh, chl, Rc * 128);
            gru_gemm2<<<24 * (Rc / 128), 256, 0, stream>>>(
                Xh + (size_t)r0 * DIM, Xl + (size_t)r0 * DIM, WiH, bih, gi,
                chh, chl, WhH, bhh, gh, DIM);
            gru_combine<<<(Rc * 128 + 255) / 256, 256, 0, stream>>>(
                gi, gh, H + (size_t)r0 * DIM, H + (size_t)r0 * DIM, Rc);
        }
    };

    // message-passing steps (in-place state in d_out)
    for (int step = 0; step < 2; step++) {
        hipMemsetAsync(nm, 0, (size_t)N_OBJS * DIM * sizeof(float), stream);
        gatepass<<<N_RELS, 256, 0, stream>>>(
            h_obj, h_edge, rel,
            g_sn_w, g_sn_b, g_on_w, g_on_b, g_se_w, g_se_b, g_oe_w, g_oe_b,
            cnt_s, cnt_o, nm, emh, eml);
        convert_hl<<<(N_OBJS * 128 + 255) / 256, 256, 0, stream>>>(
            nm, nmh, nml, N_OBJS * 128);
        run_gru(nmh, nml, h_obj, nih_h, nhh_h, ngru_bih, ngru_bhh, N_OBJS);
        run_gru(emh, eml, h_edge, eih_h, ehh_h, egru_bih, egru_bhh, N_RELS);
    }

    // classifiers (fp32 A from d_out, padded f16 weights)
    gemm_split<false, false><<<2 * (N_OBJS / 128), 256, 0, stream>>>(
        h_obj, oph, op_b, out + OFF_OLOG, nullptr, nullptr, 2, N_OBJ_CLS, DIM);
    gemm_split<false, false><<<1 * (N_RELS / 128), 256, 0, stream>>>(
        h_edge, pph, pp_b, out + OFF_PLOG, nullptr, nullptr, 1, N_REL_CLS, DIM);

    // labels + rel_inds passthrough
    argmax_kernel<<<N_OBJS / 4, 256, 0, stream>>>(out + OFF_OLOG, out + OFF_LBL);
    relinds_kernel<<<(2 * N_RELS) / 256, 256, 0, stream>>>(rel, out + OFF_RI);
}